// Round 14
// baseline (37.647 us; speedup 1.0000x reference)
//
#include <hip/hip_runtime.h>

// Problem constants (fixed by the reference)
#define NXY   16
#define NZ    8
#define NS    2048      // states = 16*16*8
#define NT    2048      // tokens
#define NB    16        // stories
#define NL    16        // story length
#define NSENT 16        // tokens per sentence
#define NEGV  (-1e9f)

// ---------------------------------------------------------------------------
// K1 v3: fused smoothing + transpose (round-6 proven body) PLUS the wtab
// prep (round-10 proven body) as extra grid blocks (blockIdx.y == 8).
// (round-12/13 proven, unchanged)
// ---------------------------------------------------------------------------
#define TT   16
#define SPAD 17

__global__ __launch_bounds__(256) void k_smooth(const float* __restrict__ em,
                                                float* __restrict__ emT,
                                                const float* __restrict__ trans,
                                                float* __restrict__ wtab) {
    const int tid = threadIdx.x;

    if (blockIdx.y == NZ) {
        // ---- prep path: one thread per (neighbor-slot, state)
        const int g = blockIdx.x * 256 + tid;          // [0, 32768)
        if (g < 7 * NS) {
            const int k = g >> 11;
            const int h = g & (NS - 1);
            const int x = h & 15, y = (h >> 4) & 15, z = h >> 8;
            const float* row = trans + (size_t)h * NS;
            float w;
            switch (k) {
                case 0: w = row[h]; break;
                case 1: w = (x < 15) ? row[h + 1]   : NEGV; break;
                case 2: w = (x > 0)  ? row[h - 1]   : NEGV; break;
                case 3: w = (y < 15) ? row[h + 16]  : NEGV; break;
                case 4: w = (y > 0)  ? row[h - 16]  : NEGV; break;
                case 5: w = (z < 7)  ? row[h + 256] : NEGV; break;
                default: w = (z < 6) ? row[h + 512] : NEGV; break;
            }
            wtab[g] = w;
        }
        return;
    }

    // ---- smooth path (round-6 body, unchanged)
    __shared__ float S[256 * SPAD];   // 17408 B
    const int t0 = blockIdx.x * TT;
    const int z = blockIdx.y;
    const int toff = tid & 15, y = tid >> 4;

    const float* base = em + ((size_t)z * 256 + y * 16) * NT + t0 + toff;
    float ex[16];
#pragma unroll
    for (int x = 0; x < 16; ++x)
        ex[x] = __expf(base[(size_t)x * NT]);

#pragma unroll
    for (int x = 0; x < 16; ++x) {
        const int xm2 = x - 2 < 0 ? 0 : x - 2, xm1 = x - 1 < 0 ? 0 : x - 1;
        const int xp1 = x + 1 > 15 ? 15 : x + 1, xp2 = x + 2 > 15 ? 15 : x + 2;
        S[(y * 16 + x) * SPAD + toff] = ex[xm2] + ex[xm1] + ex[x] + ex[xp1] + ex[xp2];
    }
    __syncthreads();

    const int x2 = tid & 15, y2 = tid >> 4;
    int ry[5];
#pragma unroll
    for (int k = 0; k < 5; ++k) {
        int yy = y2 + k - 2; yy = yy < 0 ? 0 : (yy > 15 ? 15 : yy);
        ry[k] = (yy * 16 + x2) * SPAD;
    }
    const float LOG25 = 3.2188758248682006f;   // log(5)+log(5)
    float* ob = emT + (size_t)t0 * NS + z * 256 + tid;
#pragma unroll
    for (int t = 0; t < TT; ++t) {
        float a = S[ry[0] + t] + S[ry[1] + t] + S[ry[2] + t] + S[ry[3] + t] + S[ry[4] + t];
        ob[(size_t)t * NS] = __logf(a) - LOG25;
    }
}

// ---------------------------------------------------------------------------
// K2: e_all[b,l,s] = sum_j em_T[tok[b,l,j], s]   (round-2 proven, unchanged)
// ---------------------------------------------------------------------------
__global__ __launch_bounds__(256) void k_eall(const int* __restrict__ stories,
                                              const float* __restrict__ emT,
                                              float* __restrict__ eall) {
    const int bl = blockIdx.x;
    const int col = blockIdx.y * 256 + threadIdx.x;
    __shared__ int toks[NSENT];
    if (threadIdx.x < NSENT) toks[threadIdx.x] = stories[bl * NSENT + threadIdx.x];
    __syncthreads();

    float4 a = make_float4(0.f, 0.f, 0.f, 0.f);
#pragma unroll 4
    for (int j = 0; j < NSENT; ++j) {
        float4 v = ((const float4*)(emT + (size_t)toks[j] * NS))[col];
        a.x += v.x; a.y += v.y; a.z += v.z; a.w += v.w;
    }
    ((float4*)(eall + (size_t)bl * NS))[col] = a;
}

// ---------------------------------------------------------------------------
// K3 v8: round-13 (v7) proven body + ALL 15 e-rows staged into LDS in the
// prologue (120KB, coalesced float2, full-MLP absorb of the L3 latency ONCE)
// so the 15-step loop touches only LDS + VALU + fire-and-forget out stores.
// Rationale (v6-vs-v7 A/B): steps are LATENCY-bound on the in-loop e-load,
// not LDS-issue-bound. Dynamic LDS: 15*NS + 2*NS floats = 139264 B.
// ---------------------------------------------------------------------------
__global__ __launch_bounds__(1024) void k_forward(const float* __restrict__ wtab,
                                                  const float* __restrict__ priors,
                                                  const float* __restrict__ eall,
                                                  float* __restrict__ out) {
    extern __shared__ float smem[];
    float* ebuf = smem;                    // [NL-1][NS]  (rows l=1..15)
    float* buf0 = smem + (NL - 1) * NS;    // [NS]
    float* buf1 = buf0 + NS;               // [NS]

    const int b = blockIdx.x;
    const int tid = threadIdx.x;
    const float* eb = eall + (size_t)b * NL * NS;

    // stage e rows 1..15 into LDS (fully coalesced float2, deep MLP)
    {
        const float2* src = (const float2*)(eb + NS);
        float2* dst = (float2*)ebuf;
#pragma unroll
        for (int i = 0; i < (NL - 1) * NS / 2048; ++i)     // 15 iters
            dst[i * 1024 + tid] = src[i * 1024 + tid];
    }

    float wr[2][7];
    int   ix[2][7];
#pragma unroll
    for (int p = 0; p < 2; ++p) {
        const int h = tid + p * 1024;
        const int x = h & 15, y = (h >> 4) & 15, z = h >> 8;
        wr[p][0] = wtab[0 * NS + h];  ix[p][0] = h;
        wr[p][1] = wtab[1 * NS + h];  ix[p][1] = (x < 15) ? h + 1   : h;
        wr[p][2] = wtab[2 * NS + h];  ix[p][2] = (x > 0)  ? h - 1   : h;
        wr[p][3] = wtab[3 * NS + h];  ix[p][3] = (y < 15) ? h + 16  : h;
        wr[p][4] = wtab[4 * NS + h];  ix[p][4] = (y > 0)  ? h - 16  : h;
        wr[p][5] = wtab[5 * NS + h];  ix[p][5] = (z < 7)  ? h + 256 : h;
        wr[p][6] = wtab[6 * NS + h];  ix[p][6] = (z < 6)  ? h + 512 : h;
        float v = eb[h] + priors[h];
        buf0[h] = v;
        out[(size_t)b * NS + h] = v;
    }
    __syncthreads();

    float* prev = buf0;
    float* cur = buf1;
    for (int l = 1; l < NL; ++l) {
        const float* e = ebuf + (size_t)(l - 1) * NS;     // LDS, not global
#pragma unroll
        for (int p = 0; p < 2; ++p) {
            const int h = tid + p * 1024;
            float v0 = wr[p][0] + prev[ix[p][0]];
            float v1 = wr[p][1] + prev[ix[p][1]];
            float v2 = wr[p][2] + prev[ix[p][2]];
            float v3 = wr[p][3] + prev[ix[p][3]];
            float v4 = wr[p][4] + prev[ix[p][4]];
            float v5 = wr[p][5] + prev[ix[p][5]];
            float v6 = wr[p][6] + prev[ix[p][6]];
            float m = fmaxf(fmaxf(fmaxf(v0, v1), fmaxf(v2, v3)),
                            fmaxf(fmaxf(v4, v5), v6));
            float s = __expf(v0 - m) + __expf(v1 - m) + __expf(v2 - m) + __expf(v3 - m) +
                      __expf(v4 - m) + __expf(v5 - m) + __expf(v6 - m);
            float v = e[h] + m + __logf(s);
            cur[h] = v;
            out[((size_t)l * NB + b) * NS + h] = v;      // fire-and-forget
        }
        __syncthreads();
        float* tmp = prev; prev = cur; cur = tmp;
    }
}

// ---------------------------------------------------------------------------
extern "C" void kernel_launch(void* const* d_in, const int* in_sizes, int n_in,
                              void* d_out, int out_size, void* d_ws, size_t ws_size,
                              hipStream_t stream) {
    (void)in_sizes; (void)n_in; (void)out_size; (void)ws_size;
    const int* stories  = (const int*)d_in[0];
    // d_in[1] = story_length (== NL), unused
    const float* priors = (const float*)d_in[2];
    const float* trans  = (const float*)d_in[3];
    const float* em     = (const float*)d_in[4];
    float* out = (float*)d_out;

    float* emT  = (float*)d_ws;                    // [NT][NS]    16 MB
    float* eall = emT + (size_t)NT * NS;           // [NB*NL][NS]  2 MB
    float* wtab = eall + (size_t)NB * NL * NS;     // [7][NS]     57 KB

    const int fwd_lds = ((NL - 1) * NS + 2 * NS) * (int)sizeof(float);  // 139264
    static bool attr_set = false;                  // idempotent host-side setup
    if (!attr_set) {
        hipFuncSetAttribute((const void*)k_forward,
                            hipFuncAttributeMaxDynamicSharedMemorySize, fwd_lds);
        attr_set = true;
    }

    // grid y: 0..7 = smooth z-slices, 8 = wtab prep
    k_smooth<<<dim3(NT / TT, NZ + 1), 256, 0, stream>>>(em, emT, trans, wtab);
    k_eall<<<dim3(NB * NL, 2), 256, 0, stream>>>(stories, emT, eall);
    k_forward<<<dim3(NB), 1024, fwd_lds, stream>>>(wtab, priors, eall, out);
}

// Round 15
// 37.258 us; speedup vs baseline: 1.0104x; 1.0104x over previous
//
#include <hip/hip_runtime.h>

// Problem constants (fixed by the reference)
#define NXY   16
#define NZ    8
#define NS    2048      // states = 16*16*8
#define NT    2048      // tokens
#define NB    16        // stories
#define NL    16        // story length
#define NSENT 16        // tokens per sentence
#define NEGV  (-1e9f)

// ---------------------------------------------------------------------------
// K1 v3: fused smoothing + transpose (round-6 proven body) PLUS the wtab
// prep (round-10 proven body) as extra grid blocks (blockIdx.y == 8).
// (round-12/13 proven, unchanged)
// ---------------------------------------------------------------------------
#define TT   16
#define SPAD 17

__global__ __launch_bounds__(256) void k_smooth(const float* __restrict__ em,
                                                float* __restrict__ emT,
                                                const float* __restrict__ trans,
                                                float* __restrict__ wtab) {
    const int tid = threadIdx.x;

    if (blockIdx.y == NZ) {
        // ---- prep path: one thread per (neighbor-slot, state)
        const int g = blockIdx.x * 256 + tid;          // [0, 32768)
        if (g < 7 * NS) {
            const int k = g >> 11;
            const int h = g & (NS - 1);
            const int x = h & 15, y = (h >> 4) & 15, z = h >> 8;
            const float* row = trans + (size_t)h * NS;
            float w;
            switch (k) {
                case 0: w = row[h]; break;
                case 1: w = (x < 15) ? row[h + 1]   : NEGV; break;
                case 2: w = (x > 0)  ? row[h - 1]   : NEGV; break;
                case 3: w = (y < 15) ? row[h + 16]  : NEGV; break;
                case 4: w = (y > 0)  ? row[h - 16]  : NEGV; break;
                case 5: w = (z < 7)  ? row[h + 256] : NEGV; break;
                default: w = (z < 6) ? row[h + 512] : NEGV; break;
            }
            wtab[g] = w;
        }
        return;
    }

    // ---- smooth path (round-6 body, unchanged)
    __shared__ float S[256 * SPAD];   // 17408 B
    const int t0 = blockIdx.x * TT;
    const int z = blockIdx.y;
    const int toff = tid & 15, y = tid >> 4;

    const float* base = em + ((size_t)z * 256 + y * 16) * NT + t0 + toff;
    float ex[16];
#pragma unroll
    for (int x = 0; x < 16; ++x)
        ex[x] = __expf(base[(size_t)x * NT]);

#pragma unroll
    for (int x = 0; x < 16; ++x) {
        const int xm2 = x - 2 < 0 ? 0 : x - 2, xm1 = x - 1 < 0 ? 0 : x - 1;
        const int xp1 = x + 1 > 15 ? 15 : x + 1, xp2 = x + 2 > 15 ? 15 : x + 2;
        S[(y * 16 + x) * SPAD + toff] = ex[xm2] + ex[xm1] + ex[x] + ex[xp1] + ex[xp2];
    }
    __syncthreads();

    const int x2 = tid & 15, y2 = tid >> 4;
    int ry[5];
#pragma unroll
    for (int k = 0; k < 5; ++k) {
        int yy = y2 + k - 2; yy = yy < 0 ? 0 : (yy > 15 ? 15 : yy);
        ry[k] = (yy * 16 + x2) * SPAD;
    }
    const float LOG25 = 3.2188758248682006f;   // log(5)+log(5)
    float* ob = emT + (size_t)t0 * NS + z * 256 + tid;
#pragma unroll
    for (int t = 0; t < TT; ++t) {
        float a = S[ry[0] + t] + S[ry[1] + t] + S[ry[2] + t] + S[ry[3] + t] + S[ry[4] + t];
        ob[(size_t)t * NS] = __logf(a) - LOG25;
    }
}

// ---------------------------------------------------------------------------
// K2: e_all[b,l,s] = sum_j em_T[tok[b,l,j], s]   (round-2 proven, unchanged)
// ---------------------------------------------------------------------------
__global__ __launch_bounds__(256) void k_eall(const int* __restrict__ stories,
                                              const float* __restrict__ emT,
                                              float* __restrict__ eall) {
    const int bl = blockIdx.x;
    const int col = blockIdx.y * 256 + threadIdx.x;
    __shared__ int toks[NSENT];
    if (threadIdx.x < NSENT) toks[threadIdx.x] = stories[bl * NSENT + threadIdx.x];
    __syncthreads();

    float4 a = make_float4(0.f, 0.f, 0.f, 0.f);
#pragma unroll 4
    for (int j = 0; j < NSENT; ++j) {
        float4 v = ((const float4*)(emT + (size_t)toks[j] * NS))[col];
        a.x += v.x; a.y += v.y; a.z += v.z; a.w += v.w;
    }
    ((float4*)(eall + (size_t)bl * NS))[col] = a;
}

// ---------------------------------------------------------------------------
// K3 v9: round-13 (v7) proven body with ONE change: NO global stores in the
// step loop. All 16 step-results live in LDS (res[NL][NS] = 128 KB; row l-1
// is prev, row l is cur -> the ping-pong buffers disappear), and the entire
// 2 MB output is written in an epilogue burst (16 coalesced float2 stores
// per thread, deep MLP, latency paid once).
// Rationale: R7 probe warm-rep = 13.8us vs cold ~32us; R14 proved e-loads
// cheap; the cold delta is out-stores to cold lines filling the CU store
// queue and stalling ISSUE each step (why R11's drain-removal was neutral).
// ---------------------------------------------------------------------------
__global__ __launch_bounds__(1024) void k_forward(const float* __restrict__ wtab,
                                                  const float* __restrict__ priors,
                                                  const float* __restrict__ eall,
                                                  float* __restrict__ out) {
    extern __shared__ float res[];                 // [NL][NS]  131072 B
    const int b = blockIdx.x;
    const int tid = threadIdx.x;

    float wr[2][7];
    int   ix[2][7];
#pragma unroll
    for (int p = 0; p < 2; ++p) {
        const int h = tid + p * 1024;
        const int x = h & 15, y = (h >> 4) & 15, z = h >> 8;
        wr[p][0] = wtab[0 * NS + h];  ix[p][0] = h;
        wr[p][1] = wtab[1 * NS + h];  ix[p][1] = (x < 15) ? h + 1   : h;
        wr[p][2] = wtab[2 * NS + h];  ix[p][2] = (x > 0)  ? h - 1   : h;
        wr[p][3] = wtab[3 * NS + h];  ix[p][3] = (y < 15) ? h + 16  : h;
        wr[p][4] = wtab[4 * NS + h];  ix[p][4] = (y > 0)  ? h - 16  : h;
        wr[p][5] = wtab[5 * NS + h];  ix[p][5] = (z < 7)  ? h + 256 : h;
        wr[p][6] = wtab[6 * NS + h];  ix[p][6] = (z < 6)  ? h + 512 : h;
        res[h] = eall[(size_t)b * NL * NS + h] + priors[h];   // row 0
    }
    __syncthreads();

    for (int l = 1; l < NL; ++l) {
        const float* e = eall + ((size_t)b * NL + l) * NS;    // global (cheap)
        const float* prev = res + (size_t)(l - 1) * NS;
        float* cur = res + (size_t)l * NS;
#pragma unroll
        for (int p = 0; p < 2; ++p) {
            const int h = tid + p * 1024;
            float v0 = wr[p][0] + prev[ix[p][0]];
            float v1 = wr[p][1] + prev[ix[p][1]];
            float v2 = wr[p][2] + prev[ix[p][2]];
            float v3 = wr[p][3] + prev[ix[p][3]];
            float v4 = wr[p][4] + prev[ix[p][4]];
            float v5 = wr[p][5] + prev[ix[p][5]];
            float v6 = wr[p][6] + prev[ix[p][6]];
            float m = fmaxf(fmaxf(fmaxf(v0, v1), fmaxf(v2, v3)),
                            fmaxf(fmaxf(v4, v5), v6));
            float s = __expf(v0 - m) + __expf(v1 - m) + __expf(v2 - m) + __expf(v3 - m) +
                      __expf(v4 - m) + __expf(v5 - m) + __expf(v6 - m);
            cur[h] = e[h] + m + __logf(s);
        }
        __syncthreads();
    }

    // epilogue: burst-store the whole [NL][NS] block, coalesced float2
    const int h0 = tid * 2;
#pragma unroll
    for (int l = 0; l < NL; ++l) {
        float2 v = *(const float2*)(res + (size_t)l * NS + h0);
        *(float2*)(out + ((size_t)l * NB + b) * NS + h0) = v;
    }
}

// ---------------------------------------------------------------------------
extern "C" void kernel_launch(void* const* d_in, const int* in_sizes, int n_in,
                              void* d_out, int out_size, void* d_ws, size_t ws_size,
                              hipStream_t stream) {
    (void)in_sizes; (void)n_in; (void)out_size; (void)ws_size;
    const int* stories  = (const int*)d_in[0];
    // d_in[1] = story_length (== NL), unused
    const float* priors = (const float*)d_in[2];
    const float* trans  = (const float*)d_in[3];
    const float* em     = (const float*)d_in[4];
    float* out = (float*)d_out;

    float* emT  = (float*)d_ws;                    // [NT][NS]    16 MB
    float* eall = emT + (size_t)NT * NS;           // [NB*NL][NS]  2 MB
    float* wtab = eall + (size_t)NB * NL * NS;     // [7][NS]     57 KB

    const int fwd_lds = NL * NS * (int)sizeof(float);   // 131072 B
    hipFuncSetAttribute((const void*)k_forward,
                        hipFuncAttributeMaxDynamicSharedMemorySize, fwd_lds);

    // grid y: 0..7 = smooth z-slices, 8 = wtab prep
    k_smooth<<<dim3(NT / TT, NZ + 1), 256, 0, stream>>>(em, emT, trans, wtab);
    k_eall<<<dim3(NB * NL, 2), 256, 0, stream>>>(stories, emT, eall);
    k_forward<<<dim3(NB), 1024, fwd_lds, stream>>>(wtab, priors, eall, out);
}